// Round 6
// baseline (90.335 us; speedup 1.0000x reference)
//
#include <hip/hip_runtime.h>
#include <hip/hip_bf16.h>

// DiversityLoss: attention_maps [B=64, M=32, H*W=16384] fp32.
// gram[b,i,j] = sum_k (A[b,i,k]^2 * A[b,j,k]^2); loss = mean_b sum_{i<j} relu(0.1-gram)/496.
//
// R4 (bf16 MFMA, A-frag==B-frag, no LDS in loop): 46.5 us total -- gram likely
// latency-exposed (full-unroll load burst, high VGPR) + ~12-18 us of serial tail
// (2 extra dispatches). R5/R6: (a) depth-limited pipeline (unroll 4, ~8 loads in
// flight, low VGPR -> all 16 waves/CU resident); (b) tail fused into the gram
// kernel via "last block per batch reduces" with __threadfence() (agent scope --
// XCD L2s are not cross-coherent) -- deterministic: every sum done by ONE block
// in fixed index order. R5 failed: __hip_atomic_fence not declared in this ROCm;
// use __threadfence() + atomicAdd (device-scope by default, m20).
// Precision: gram ~= K/9 ~= 1820 >> margin 0.1; bf16 MFMA safely sufficient.

#define MARGIN 0.1f

constexpr int B_ = 64;
constexpr int M_ = 32;
constexpr int K_ = 16384;
constexpr int NC = 16;           // k-chunks per batch -> grid 1024 = 4 blocks/CU
constexpr int KC = K_ / NC;      // 1024 k per block; 256 per wave; 16 MFMA steps

typedef __attribute__((ext_vector_type(8))) short bf16x8;
typedef __attribute__((ext_vector_type(16))) float f32x16;

static __device__ __forceinline__ short f2bf(float f) {
  return __builtin_bit_cast(short, __float2bfloat16(f));
}

// Counters must start at 0 every call (they end at 16/64) -> tiny init dispatch.
__global__ void init_counters(unsigned* __restrict__ cnt) {
  if (threadIdx.x < 65) cnt[threadIdx.x] = 0;
}

__global__ __launch_bounds__(256) void gram_fused(const float* __restrict__ A,
                                                  float* __restrict__ ws_g,
                                                  float* __restrict__ ws_b,
                                                  unsigned* __restrict__ cnt,
                                                  float* __restrict__ out) {
  const int tid  = threadIdx.x;
  const int w    = tid >> 6;       // wave 0..3
  const int lane = tid & 63;
  const int b    = blockIdx.x >> 4;
  const int c    = blockIdx.x & (NC - 1);
  const int row  = lane & 31;      // gram row/col this lane feeds (A and B roles)
  const int kh   = lane >> 5;      // k-half within a 16-k MFMA step

  // lane's stream: row (lane&31), k in [c*KC + w*256, +256), 16 elems/step (2 float4)
  const size_t ebase = (size_t)(b * M_ + row) * K_ + (size_t)c * KC + w * (KC / 4) + (size_t)kh * 8;
  const float4* p = reinterpret_cast<const float4*>(A + ebase);

  f32x16 acc = {};
#pragma unroll 4
  for (int s = 0; s < 16; ++s) {
    const float4 f0 = p[s * 4 + 0];
    const float4 f1 = p[s * 4 + 1];
    bf16x8 frag;
    frag[0] = f2bf(f0.x * f0.x);
    frag[1] = f2bf(f0.y * f0.y);
    frag[2] = f2bf(f0.z * f0.z);
    frag[3] = f2bf(f0.w * f0.w);
    frag[4] = f2bf(f1.x * f1.x);
    frag[5] = f2bf(f1.y * f1.y);
    frag[6] = f2bf(f1.z * f1.z);
    frag[7] = f2bf(f1.w * f1.w);
    acc = __builtin_amdgcn_mfma_f32_32x32x16_bf16(frag, frag, acc, 0, 0, 0);
  }

  // Cross-wave k-reduce in LDS.
  // C/D layout (HW-verified m74/m101): col = lane&31, row = (r&3) + 8*(r>>2) + 4*(lane>>5)
  __shared__ float red[4][M_ * M_];  // 16 KiB
  __shared__ unsigned flag1, flag2;
#pragma unroll
  for (int r = 0; r < 16; ++r) {
    const int rr = (r & 3) + 8 * (r >> 2) + 4 * kh;
    red[w][rr * 32 + row] = acc[r];
  }
  __syncthreads();

  const float4* R4 = reinterpret_cast<const float4*>(&red[0][0]);
  const float4 s0 = R4[tid], s1 = R4[256 + tid], s2 = R4[512 + tid], s3 = R4[768 + tid];
  float4 o;
  o.x = s0.x + s1.x + s2.x + s3.x;
  o.y = s0.y + s1.y + s2.y + s3.y;
  o.z = s0.z + s1.z + s2.z + s3.z;
  o.w = s0.w + s1.w + s2.w + s3.w;
  reinterpret_cast<float4*>(ws_g)[(size_t)blockIdx.x * 256 + tid] = o;

  // --- fused tail: last block of each batch reduces that batch ---
  __syncthreads();  // all threads' ws_g stores issued before the flag
  if (tid == 0) {
    __threadfence();  // agent-scope release: ws_g visible across XCD L2s
    flag1 = atomicAdd(&cnt[b], 1u);  // device-scope (m20)
  }
  __syncthreads();

  if (flag1 == NC - 1) {  // block-uniform: this block is last for batch b
    if (tid == 0) __threadfence();  // acquire side
    __syncthreads();
    const float4* G4 = reinterpret_cast<const float4*>(ws_g);
    float4 g = make_float4(0.f, 0.f, 0.f, 0.f);
#pragma unroll
    for (int cc = 0; cc < NC; ++cc) {
      const float4 t = G4[((size_t)(b * NC + cc)) * 256 + tid];
      g.x += t.x; g.y += t.y; g.z += t.z; g.w += t.w;
    }
    const float gv[4] = {g.x, g.y, g.z, g.w};
    float local = 0.f;
#pragma unroll
    for (int e = 0; e < 4; ++e) {
      const int idx = tid * 4 + e;
      if ((idx & 31) > (idx >> 5)) local += fmaxf(MARGIN - gv[e], 0.0f);  // strict upper
    }
#pragma unroll
    for (int off = 32; off > 0; off >>= 1) local += __shfl_down(local, off);
    if (lane == 0) red[0][w] = local;
    __syncthreads();

    if (tid == 0) {
      ws_b[b] = (red[0][0] + red[0][1] + red[0][2] + red[0][3]) * (1.0f / 496.0f);
      __threadfence();  // release ws_b
      flag2 = atomicAdd(&cnt[64], 1u);
    }
    __syncthreads();

    if (flag2 == B_ - 1 && w == 0) {  // very last batch: wave 0 does the mean
      if (lane == 0) __threadfence();  // acquire side
      __builtin_amdgcn_wave_barrier();
      float v = ws_b[lane];
#pragma unroll
      for (int off = 32; off > 0; off >>= 1) v += __shfl_down(v, off);
      if (lane == 0) out[0] = v * (1.0f / 64.0f);
    }
  }
}

extern "C" void kernel_launch(void* const* d_in, const int* in_sizes, int n_in,
                              void* d_out, int out_size, void* d_ws, size_t ws_size,
                              hipStream_t stream) {
  const float* A = reinterpret_cast<const float*>(d_in[0]);
  float* out = reinterpret_cast<float*>(d_out);

  // ws: [1024][1024] partial grams (4 MiB) + 64 batch losses + 65 counters
  float* ws_g = reinterpret_cast<float*>(d_ws);
  float* ws_b = ws_g + (size_t)B_ * NC * M_ * M_;
  unsigned* cnt = reinterpret_cast<unsigned*>(ws_b + B_);

  init_counters<<<1, 128, 0, stream>>>(cnt);
  gram_fused<<<B_ * NC, 256, 0, stream>>>(A, ws_g, ws_b, cnt, out);
}

// Round 7
// 90.128 us; speedup vs baseline: 1.0023x; 1.0023x over previous
//
#include <hip/hip_runtime.h>
#include <hip/hip_bf16.h>

// DiversityLoss: attention_maps [B=64, M=32, H*W=16384] fp32.
// gram[b,i,j] = sum_k (A[b,i,k]^2 * A[b,j,k]^2); loss = mean_b sum_{i<j} relu(0.1-gram)/496.
//
// R6 post-mortem: unroll-4 -> compiler kept only ~2 loads in flight (VGPR=44),
// VALUBusy 1%, latency-bound at 123 us; L3-warm replays equally slow -> pure MLP
// starvation. R7: explicit 8-deep rolling prefetch buffer (statically indexed --
// runtime-indexed arrays spill to scratch), ~100 VGPR, 16 KB/wave in flight.
// MFMA trick unchanged: for S*S^T, A-frag == B-frag (lane l holds S[l&31][..]);
// k-permutations cancel, result symmetric. Tail fused via "last block per batch"
// counters + __threadfence (agent scope; XCD L2s not cross-coherent), fixed
// summation order -> deterministic. Precision: gram ~= K/9 ~= 1820 >> 0.1 margin.

#define MARGIN 0.1f

constexpr int B_ = 64;
constexpr int M_ = 32;
constexpr int K_ = 16384;
constexpr int NC = 16;           // k-chunks per batch -> grid 1024 = 4 blocks/CU
constexpr int KC = K_ / NC;      // 1024 k per block; 256 per wave; 16 MFMA steps
constexpr int PF = 8;            // prefetch depth (float4-pairs in flight)

typedef __attribute__((ext_vector_type(8))) short bf16x8;
typedef __attribute__((ext_vector_type(16))) float f32x16;

static __device__ __forceinline__ short f2bf(float f) {
  return __builtin_bit_cast(short, __float2bfloat16(f));
}

// Counters must start at 0 every call (they end at 16/64) -> tiny init dispatch.
__global__ void init_counters(unsigned* __restrict__ cnt) {
  if (threadIdx.x < 65) cnt[threadIdx.x] = 0;
}

__global__ __launch_bounds__(256) void gram_fused(const float* __restrict__ A,
                                                  float* __restrict__ ws_g,
                                                  float* __restrict__ ws_b,
                                                  unsigned* __restrict__ cnt,
                                                  float* __restrict__ out) {
  const int tid  = threadIdx.x;
  const int w    = tid >> 6;       // wave 0..3
  const int lane = tid & 63;
  const int b    = blockIdx.x >> 4;
  const int c    = blockIdx.x & (NC - 1);
  const int row  = lane & 31;      // gram row/col this lane feeds (A and B roles)
  const int kh   = lane >> 5;      // k-half within a 16-k MFMA step

  // lane's stream: row (lane&31), k in [c*KC + w*256, +256), 16 elems/step (2 float4)
  const size_t ebase = (size_t)(b * M_ + row) * K_ + (size_t)c * KC + w * (KC / 4) + (size_t)kh * 8;
  const float4* p = reinterpret_cast<const float4*>(A + ebase);

  // explicit 8-deep rolling prefetch; ALL indices compile-time (full unroll)
  float4 v0[PF], v1[PF];
#pragma unroll
  for (int i = 0; i < PF; ++i) {
    v0[i] = p[i * 4 + 0];
    v1[i] = p[i * 4 + 1];
  }

  f32x16 acc = {};
#pragma unroll
  for (int s = 0; s < 16; ++s) {
    const float4 f0 = v0[s & (PF - 1)];
    const float4 f1 = v1[s & (PF - 1)];
    if (s + PF < 16) {
      v0[s & (PF - 1)] = p[(s + PF) * 4 + 0];
      v1[s & (PF - 1)] = p[(s + PF) * 4 + 1];
    }
    bf16x8 frag;
    frag[0] = f2bf(f0.x * f0.x);
    frag[1] = f2bf(f0.y * f0.y);
    frag[2] = f2bf(f0.z * f0.z);
    frag[3] = f2bf(f0.w * f0.w);
    frag[4] = f2bf(f1.x * f1.x);
    frag[5] = f2bf(f1.y * f1.y);
    frag[6] = f2bf(f1.z * f1.z);
    frag[7] = f2bf(f1.w * f1.w);
    acc = __builtin_amdgcn_mfma_f32_32x32x16_bf16(frag, frag, acc, 0, 0, 0);
  }

  // Cross-wave k-reduce in LDS.
  // C/D layout (HW-verified m74/m101): col = lane&31, row = (r&3) + 8*(r>>2) + 4*(lane>>5)
  __shared__ float red[4][M_ * M_];  // 16 KiB
  __shared__ unsigned flag1, flag2;
#pragma unroll
  for (int r = 0; r < 16; ++r) {
    const int rr = (r & 3) + 8 * (r >> 2) + 4 * kh;
    red[w][rr * 32 + row] = acc[r];
  }
  __syncthreads();

  const float4* R4 = reinterpret_cast<const float4*>(&red[0][0]);
  const float4 s0 = R4[tid], s1 = R4[256 + tid], s2 = R4[512 + tid], s3 = R4[768 + tid];
  float4 o;
  o.x = s0.x + s1.x + s2.x + s3.x;
  o.y = s0.y + s1.y + s2.y + s3.y;
  o.z = s0.z + s1.z + s2.z + s3.z;
  o.w = s0.w + s1.w + s2.w + s3.w;
  reinterpret_cast<float4*>(ws_g)[(size_t)blockIdx.x * 256 + tid] = o;

  // --- fused tail: last block of each batch reduces that batch ---
  __syncthreads();  // all threads' ws_g stores issued before the flag
  if (tid == 0) {
    __threadfence();  // agent-scope release: ws_g visible across XCD L2s
    flag1 = atomicAdd(&cnt[b], 1u);  // device-scope (m20)
  }
  __syncthreads();

  if (flag1 == NC - 1) {  // block-uniform: this block is last for batch b
    if (tid == 0) __threadfence();  // acquire side
    __syncthreads();
    const float4* G4 = reinterpret_cast<const float4*>(ws_g);
    float4 g = make_float4(0.f, 0.f, 0.f, 0.f);
#pragma unroll
    for (int cc = 0; cc < NC; ++cc) {
      const float4 t = G4[((size_t)(b * NC + cc)) * 256 + tid];
      g.x += t.x; g.y += t.y; g.z += t.z; g.w += t.w;
    }
    const float gv[4] = {g.x, g.y, g.z, g.w};
    float local = 0.f;
#pragma unroll
    for (int e = 0; e < 4; ++e) {
      const int idx = tid * 4 + e;
      if ((idx & 31) > (idx >> 5)) local += fmaxf(MARGIN - gv[e], 0.0f);  // strict upper
    }
#pragma unroll
    for (int off = 32; off > 0; off >>= 1) local += __shfl_down(local, off);
    if (lane == 0) red[0][w] = local;
    __syncthreads();

    if (tid == 0) {
      ws_b[b] = (red[0][0] + red[0][1] + red[0][2] + red[0][3]) * (1.0f / 496.0f);
      __threadfence();  // release ws_b
      flag2 = atomicAdd(&cnt[64], 1u);
    }
    __syncthreads();

    if (flag2 == B_ - 1 && w == 0) {  // very last batch: wave 0 does the mean
      if (lane == 0) __threadfence();  // acquire side
      __builtin_amdgcn_wave_barrier();
      float v = ws_b[lane];
#pragma unroll
      for (int off = 32; off > 0; off >>= 1) v += __shfl_down(v, off);
      if (lane == 0) out[0] = v * (1.0f / 64.0f);
    }
  }
}

extern "C" void kernel_launch(void* const* d_in, const int* in_sizes, int n_in,
                              void* d_out, int out_size, void* d_ws, size_t ws_size,
                              hipStream_t stream) {
  const float* A = reinterpret_cast<const float*>(d_in[0]);
  float* out = reinterpret_cast<float*>(d_out);

  // ws: [1024][1024] partial grams (4 MiB) + 64 batch losses + 65 counters
  float* ws_g = reinterpret_cast<float*>(d_ws);
  float* ws_b = ws_g + (size_t)B_ * NC * M_ * M_;
  unsigned* cnt = reinterpret_cast<unsigned*>(ws_b + B_);

  init_counters<<<1, 128, 0, stream>>>(cnt);
  gram_fused<<<B_ * NC, 256, 0, stream>>>(A, ws_g, ws_b, cnt, out);
}